// Round 6
// baseline (675.112 us; speedup 1.0000x reference)
//
#include <hip/hip_runtime.h>
#include <hip/hip_bf16.h>

// MAMBA2_2D fused kernel, round 6.
// - uA fragments cached in VGPRs (wave owns m-tile mt=w>>1 everywhere)
// - z computed tile-in-registers (C-layout matches Y) -> no zh buffer
// - D folded into M diagonal -> no x re-read in gating
// - ssq in registers, one reduce at end
// - 2 barriers/head (D5 of head h runs in phase-1 of head h+1)
// LDS ~54.3 KB, 2 blocks/CU. Output float32.

#define NTH 512

typedef __attribute__((ext_vector_type(8))) short short8;
typedef __attribute__((ext_vector_type(4))) float floatx4;

__device__ __forceinline__ float silu_f(float v){ return v / (1.f + __expf(-v)); }
__device__ __forceinline__ float softplus_f(float v){
  return fmaxf(v, 0.f) + log1pf(__expf(-fabsf(v)));
}
__device__ __forceinline__ short f2bs(float v){
  __hip_bfloat16 h = __float2bfloat16(v);
  return *reinterpret_cast<short*>(&h);
}
__device__ __forceinline__ float bs2f(short s){
  __hip_bfloat16 h = *reinterpret_cast<__hip_bfloat16*>(&s);
  return __bfloat162float(h);
}
__device__ __forceinline__ unsigned int pk2(float a, float b){
  return (unsigned int)(unsigned short)f2bs(a) | ((unsigned int)(unsigned short)f2bs(b) << 16);
}

__global__ void setup_weights(const float* __restrict__ fc_w,
                              const float* __restrict__ how, const float* __restrict__ hnw,
                              const float* __restrict__ vow, const float* __restrict__ vnw,
                              const float* __restrict__ hw, const float* __restrict__ vw,
                              __hip_bfloat16* __restrict__ Wc,
                              __hip_bfloat16* __restrict__ inw)
{
  int b = blockIdx.x;
  if (b < 1024) {
    int id = b * 256 + threadIdx.x;           // 262144
    int dir = id >> 17;
    int r = id & 131071;
    int o = r >> 9, j = r & 511;
    const float* ow = dir ? vow : how;
    const float* nw = dir ? vnw : hnw;
    int off = dir ? 0 : 512;
    const float* fr = fc_w + o * 1024 + off;
    float acc = 0.f;
    for (int k = 0; k < 256; ++k) acc += (fr[k] + fr[256 + k]) * ow[k * 512 + j];
    Wc[id] = __float2bfloat16(nw[j] * acc);
  } else {
    int id = (b - 1024) * 256 + threadIdx.x;  // 598016 = 2*1168*256
    int dir = id / 299008;
    int r = id % 299008;
    int row = r >> 8;
    const float* src = dir ? vw : hw;
    float v = (row < 1160) ? src[r] : 0.f;
    inw[id] = __float2bfloat16(v);
  }
}

// LDS short-offsets (55616 B total)
#define OFS_XRAW 0       // bf16 [64][68] x-raw [p][t]          (overlays smU/smB)
#define OFS_X    4352    // bf16 [64][72] X [p][s]              (overlays smU/smC)
#define OFS_M    8960    // bf16 [64][72] M [t][s]              (overlays smU/smC tail)
#define OFS_GB   16896   // bf16 [64][72] g [t][j]              (overlays R1bc)
#define OFS_G    21504   // bf16 [64][65] G [t][s]              (overlays R1bc)
#define OFS_R1   16896   // bf16 [136][68] BCdt raw (prologue only)
#define OFS_B    0       // bf16 [64][72] B [s][n] (prologue only)
#define OFS_C    4608    // bf16 [64][72] C [t][n] (prologue only)
#define OFS_CUM  26144   // fp32 [8][64]
#define OFS_DT   27168   // bf16 [8][64]
#define OFS_SSQ  27680   // fp32 [64]
#define SM_SHORTS 27808

template<int DIR>
__global__ __launch_bounds__(NTH, 4)
void mamba_dir_kernel(const float* __restrict__ x,
                      const __hip_bfloat16* __restrict__ inw_bf,  // [1168][256]
                      const float* __restrict__ conv_w,
                      const float* __restrict__ conv_b,
                      const float* __restrict__ dt_bias,
                      const float* __restrict__ A_log,
                      const float* __restrict__ Dvec,
                      const __hip_bfloat16* __restrict__ Wc,      // [256][512]
                      const float* __restrict__ fc_b,
                      float* __restrict__ out)
{
  __shared__ short sm[SM_SHORTS];
  short* smU   = sm;                    // bf16 [64][264] staging (prologue only)
  short* xraw  = sm + OFS_XRAW;
  short* smX   = sm + OFS_X;
  short* smM   = sm + OFS_M;
  short* smg   = sm + OFS_GB;
  short* smG   = sm + OFS_G;
  short* smR1  = sm + OFS_R1;
  short* smB   = sm + OFS_B;
  short* smC   = sm + OFS_C;
  float* smCUM = (float*)(sm + OFS_CUM);
  short* smDT  = sm + OFS_DT;
  float* smSSQ = (float*)(sm + OFS_SSQ);

  const int tid = threadIdx.x;
  const int t = tid & 63;
  const int w = tid >> 6;
  const int lane15 = tid & 15;
  const int quad = (tid & 63) >> 4;
  const int mt = w >> 1;               // wave's m-tile (t rows mt*16..+15)
  const int nt0 = (w & 1) * 2;         // wave's first n-tile for 64-col outputs
  const int s = blockIdx.x;

  auto MF = [](short8 a, short8 b, floatx4 c) -> floatx4 {
    return __builtin_amdgcn_mfma_f32_16x16x32_bf16(a, b, c, 0, 0, 0);
  };
  auto ldB_w = [&](int row0, int kt) -> short8 {
    return *(const short8*)((const short*)inw_bf + (row0 + lane15) * 256 + kt * 32 + quad * 8);
  };
  auto ldB_wc = [&](int o0, int hd, int kt) -> short8 {
    return *(const short8*)((const short*)Wc + (o0 + lane15) * 512 + hd * 64 + kt * 32 + quad * 8);
  };
  auto ld72 = [&](const short* base, int row, int kt) -> short8 {
    return *(const short8*)(base + row * 72 + kt * 32 + quad * 8);
  };

  long ubase; int ustride;
  if (DIR == 0) { ubase = (long)s * 16384; ustride = 256; }
  else { ubase = (long)(s >> 6) * 1048576 + (long)(s & 63) * 256; ustride = 16384; }

  // ---- stage u -> bf16 [t][264] ----
  for (int i = tid; i < 4096; i += NTH) {
    int tt = i >> 6, c4 = (i & 63) * 4;
    const float4 v = *(const float4*)(x + ubase + (long)tt * ustride + c4);
    uint2 pw; pw.x = pk2(v.x, v.y); pw.y = pk2(v.z, v.w);
    *(uint2*)(smU + tt * 264 + c4) = pw;
  }
  if (tid < 64) smSSQ[tid] = 0.f;
  __syncthreads();

  // ---- cache A-fragments of u for this wave's m-tile (32 VGPRs) ----
  short8 uA[8];
#pragma unroll
  for (int kt = 0; kt < 8; ++kt)
    uA[kt] = *(const short8*)(smU + (mt * 16 + lane15) * 264 + kt * 32 + quad * 8);
  __syncthreads();   // smU dead; region reused below

  // ---- BCdt projection -> smR1 bf16 [136][68] [ch][t] ----
  {
    int ntA = (w & 1) ? 5 : 0, ntE = (w & 1) ? 9 : 5;
    for (int nt = ntA; nt < ntE; ++nt) {
      floatx4 a = (floatx4)0.f;
#pragma unroll
      for (int kt = 0; kt < 8; ++kt) a = MF(uA[kt], ldB_w(1024 + nt * 16, kt), a);
      int q = nt * 16 + lane15;
      if (q < 136) {
        uint2 pw; pw.x = pk2(a[0], a[1]); pw.y = pk2(a[2], a[3]);
        *(uint2*)(smR1 + q * 68 + mt * 16 + quad * 4) = pw;
      }
    }
  }
  __syncthreads();

  // ---- conv+silu B/C -> smB [s][n] / smC [t][n]; dt softplus + cum scan ----
  {
#pragma unroll
    for (int ii = 0; ii < 16; ++ii) {
      int q = w + ii * 8;            // 0..127
      int ch = 512 + q;
      const short* base = smR1 + q * 68 + t;
      float v3 = bs2f(base[0]);
      float v2 = (t >= 1) ? bs2f(base[-1]) : 0.f;
      float v1 = (t >= 2) ? bs2f(base[-2]) : 0.f;
      float v0 = (t >= 3) ? bs2f(base[-3]) : 0.f;
      const float4 cw = *(const float4*)(conv_w + ch * 4);
      float v = cw.x*v0 + cw.y*v1 + cw.z*v2 + cw.w*v3 + conv_b[ch];
      short sv = f2bs(silu_f(v));
      if (q < 64) smB[t * 72 + q] = sv;
      else        smC[t * 72 + (q - 64)] = sv;
    }
    float dtv = softplus_f(bs2f(smR1[(128 + w) * 68 + t]) + dt_bias[w]);
    smDT[w * 64 + t] = f2bs(dtv);
    float cum = -__expf(A_log[w]) * dtv;
#pragma unroll
    for (int off = 1; off < 64; off <<= 1) {
      float y = __shfl_up(cum, off, 64);
      if (t >= off) cum += y;
    }
    smCUM[w * 64 + t] = cum;
  }
  __syncthreads();

  // ---- G = C B^T -> smG bf16 [t][65] ----
  {
    floatx4 g0 = (floatx4)0.f, g1 = (floatx4)0.f;
#pragma unroll
    for (int kt = 0; kt < 2; ++kt) {
      short8 a  = ld72(smC, mt * 16 + lane15, kt);
      g0 = MF(a, ld72(smB, nt0 * 16 + lane15, kt), g0);
      g1 = MF(a, ld72(smB, (nt0 + 1) * 16 + lane15, kt), g1);
    }
#pragma unroll
    for (int r = 0; r < 4; ++r) {
      int tt = mt * 16 + quad * 4 + r;
      smG[tt * 65 + nt0 * 16 + lane15]       = f2bs(g0[r]);
      smG[tt * 65 + (nt0 + 1) * 16 + lane15] = f2bs(g1[r]);
    }
  }
  __syncthreads();   // G done; smB/smC dead

  floatx4 accO[8];
#pragma unroll
  for (int n = 0; n < 8; ++n) accO[n] = (floatx4)0.f;
  float part[4] = {0.f, 0.f, 0.f, 0.f};

  // x-projection of a head into xraw [p][t]
  auto xproj = [&](int hd) {
#pragma unroll
    for (int j = 0; j < 2; ++j) {
      floatx4 a = (floatx4)0.f;
#pragma unroll
      for (int kt = 0; kt < 8; ++kt)
        a = MF(uA[kt], ldB_w(512 + hd * 64 + (nt0 + j) * 16, kt), a);
      uint2 pw; pw.x = pk2(a[0], a[1]); pw.y = pk2(a[2], a[3]);
      *(uint2*)(xraw + ((nt0 + j) * 16 + lane15) * 68 + mt * 16 + quad * 4) = pw;
    }
  };
  // out-projection accumulate for head h (reads smg)
  auto d5 = [&](int h) {
    short8 ag0 = ld72(smg, mt * 16 + lane15, 0);
    short8 ag1 = ld72(smg, mt * 16 + lane15, 1);
#pragma unroll
    for (int n2 = 0; n2 < 8; ++n2) {
      int o0 = ((w & 1) * 8 + n2) * 16;
      accO[n2] = MF(ag0, ldB_wc(o0, h, 0), accO[n2]);
      accO[n2] = MF(ag1, ldB_wc(o0, h, 1), accO[n2]);
    }
  };

  xproj(0);

  for (int hd = 0; hd < 8; ++hd) {
    __syncthreads();                 // B1: xraw(hd), smg(hd-1) ready; smM/smX free
    if (hd) d5(hd - 1);

    // conv+silu x -> smX [p][s]
#pragma unroll
    for (int ii = 0; ii < 8; ++ii) {
      int p = w + ii * 8, ch = hd * 64 + p;
      const short* base = xraw + p * 68 + t;
      float v3 = bs2f(base[0]);
      float v2 = (t >= 1) ? bs2f(base[-1]) : 0.f;
      float v1 = (t >= 2) ? bs2f(base[-2]) : 0.f;
      float v0 = (t >= 3) ? bs2f(base[-3]) : 0.f;
      const float4 cw = *(const float4*)(conv_w + ch * 4);
      float v = cw.x*v0 + cw.y*v1 + cw.z*v2 + cw.w*v3 + conv_b[ch];
      smX[p * 72 + t] = f2bs(silu_f(v));
    }
    // M build (D folded into diagonal) -> smM [t][s]
    {
      const float* cumh = smCUM + hd * 64;
      const short* dth  = smDT + hd * 64;
      float Dh = Dvec[hd];
      float cs = cumh[t];
      float dv = bs2f(dth[t]);
#pragma unroll
      for (int k = 0; k < 8; ++k) {
        int tt = k * 8 + w;
        float m = 0.f;
        if (tt >= t) m = __expf(cumh[tt] - cs) * dv * bs2f(smG[tt * 65 + t]);
        if (tt == t) m += Dh;
        smM[tt * 72 + t] = f2bs(m);
      }
    }
    __syncthreads();                 // B2: smM/smX ready

    // Y = M X (LDS) ; z tile in regs (global B) ; gating -> smg
    {
      floatx4 y0 = (floatx4)0.f, y1 = (floatx4)0.f;
#pragma unroll
      for (int kt = 0; kt < 2; ++kt) {
        short8 a = ld72(smM, mt * 16 + lane15, kt);
        y0 = MF(a, ld72(smX, nt0 * 16 + lane15, kt), y0);
        y1 = MF(a, ld72(smX, (nt0 + 1) * 16 + lane15, kt), y1);
      }
      floatx4 z0 = (floatx4)0.f, z1 = (floatx4)0.f;
#pragma unroll
      for (int kt = 0; kt < 8; ++kt) {
        z0 = MF(uA[kt], ldB_w(hd * 64 + nt0 * 16, kt), z0);
        z1 = MF(uA[kt], ldB_w(hd * 64 + (nt0 + 1) * 16, kt), z1);
      }
#pragma unroll
      for (int j = 0; j < 2; ++j) {
        floatx4 yy = j ? y1 : y0;
        floatx4 zz = j ? z1 : z0;
        int p = (nt0 + j) * 16 + lane15;
#pragma unroll
        for (int r = 0; r < 4; ++r) {
          float g = yy[r] * silu_f(zz[r]);
          part[r] += g * g;
          smg[(mt * 16 + quad * 4 + r) * 72 + p] = f2bs(g);
        }
      }
    }
    if (hd < 7) xproj(hd + 1);
  }

  __syncthreads();                   // smg(7) ready
  d5(7);

  // ---- ssq reduce (over the 16 lanes sharing a tr) ----
#pragma unroll
  for (int r = 0; r < 4; ++r) {
    float v = part[r];
    v += __shfl_xor(v, 1, 64);
    v += __shfl_xor(v, 2, 64);
    v += __shfl_xor(v, 4, 64);
    v += __shfl_xor(v, 8, 64);
    if (lane15 == 0) atomicAdd(&smSSQ[mt * 16 + quad * 4 + r], v);
  }
  __syncthreads();

  // ---- epilogue ----
  float rms[4];
#pragma unroll
  for (int r = 0; r < 4; ++r)
    rms[r] = rsqrtf(smSSQ[mt * 16 + quad * 4 + r] * (1.f / 512.f) + 1e-5f);
#pragma unroll
  for (int n2 = 0; n2 < 8; ++n2) {
    int o = ((w & 1) * 8 + n2) * 16 + lane15;
    float fb = (DIR == 0) ? fc_b[o] : 0.f;
#pragma unroll
    for (int r = 0; r < 4; ++r) {
      int tt = mt * 16 + quad * 4 + r;
      float val = accO[n2][r] * rms[r];
      long rowg = (DIR == 0) ? ((long)s * 64 + tt)
                             : ((long)(s >> 6) * 4096 + (long)tt * 64 + (s & 63));
      long gi = rowg * 256 + o;
      if (DIR == 0) out[gi] = fb + val;
      else          out[gi] += val;
    }
  }
}

extern "C" void kernel_launch(void* const* d_in, const int* in_sizes, int n_in,
                              void* d_out, int out_size, void* d_ws, size_t ws_size,
                              hipStream_t stream) {
  const float* x          = (const float*)d_in[0];
  const float* mh_in_w    = (const float*)d_in[1];
  const float* mh_conv_w  = (const float*)d_in[2];
  const float* mh_conv_b  = (const float*)d_in[3];
  const float* mh_dt_bias = (const float*)d_in[4];
  const float* mh_A_log   = (const float*)d_in[5];
  const float* mh_D       = (const float*)d_in[6];
  const float* mh_norm_w  = (const float*)d_in[7];
  const float* mh_out_w   = (const float*)d_in[8];
  const float* mv_in_w    = (const float*)d_in[9];
  const float* mv_conv_w  = (const float*)d_in[10];
  const float* mv_conv_b  = (const float*)d_in[11];
  const float* mv_dt_bias = (const float*)d_in[12];
  const float* mv_A_log   = (const float*)d_in[13];
  const float* mv_D       = (const float*)d_in[14];
  const float* mv_norm_w  = (const float*)d_in[15];
  const float* mv_out_w   = (const float*)d_in[16];
  const float* fc_w       = (const float*)d_in[17];
  const float* fc_b       = (const float*)d_in[18];
  float* out = (float*)d_out;

  __hip_bfloat16* Wcb  = (__hip_bfloat16*)d_ws;                       // 2*131072 bf16
  __hip_bfloat16* inwb = (__hip_bfloat16*)((char*)d_ws + 524288);     // 2*1168*256 bf16

  setup_weights<<<3360, 256, 0, stream>>>(fc_w, mh_out_w, mh_norm_w, mv_out_w, mv_norm_w,
                                          mh_in_w, mv_in_w, Wcb, inwb);
  mamba_dir_kernel<0><<<512, NTH, 0, stream>>>(x, inwb, mh_conv_w, mh_conv_b,
      mh_dt_bias, mh_A_log, mh_D, Wcb, fc_b, out);
  mamba_dir_kernel<1><<<512, NTH, 0, stream>>>(x, inwb + 299008, mv_conv_w, mv_conv_b,
      mv_dt_bias, mv_A_log, mv_D, Wcb + 131072, fc_b, out);
}

// Round 7
// 369.667 us; speedup vs baseline: 1.8263x; 1.8263x over previous
//
#include <hip/hip_runtime.h>
#include <hip/hip_bf16.h>

// MAMBA2_2D fused kernel, round 7 = round-5 structure (n-tile wave ownership,
// 4:1 MFMA:weight-load amortization) + structure-independent wins from r6:
// D folded into M diagonal, ssq in registers, G kept in registers (no smG),
// dedicated smg buffer -> 3 barriers/head. LDS 81408 B, 2 blocks/CU.

#define NTH 512

typedef __attribute__((ext_vector_type(8))) short short8;
typedef __attribute__((ext_vector_type(4))) float floatx4;

__device__ __forceinline__ float silu_f(float v){ return v / (1.f + __expf(-v)); }
__device__ __forceinline__ float softplus_f(float v){
  return fmaxf(v, 0.f) + log1pf(__expf(-fabsf(v)));
}
__device__ __forceinline__ short f2bs(float v){
  __hip_bfloat16 h = __float2bfloat16(v);
  return *reinterpret_cast<short*>(&h);
}
__device__ __forceinline__ float bs2f(short s){
  __hip_bfloat16 h = *reinterpret_cast<__hip_bfloat16*>(&s);
  return __bfloat162float(h);
}
__device__ __forceinline__ unsigned int pk2(float a, float b){
  return (unsigned int)(unsigned short)f2bs(a) | ((unsigned int)(unsigned short)f2bs(b) << 16);
}

__global__ void setup_weights(const float* __restrict__ fc_w,
                              const float* __restrict__ how, const float* __restrict__ hnw,
                              const float* __restrict__ vow, const float* __restrict__ vnw,
                              const float* __restrict__ hw, const float* __restrict__ vw,
                              __hip_bfloat16* __restrict__ Wc,
                              __hip_bfloat16* __restrict__ inw)
{
  int b = blockIdx.x;
  if (b < 1024) {
    int id = b * 256 + threadIdx.x;           // 262144
    int dir = id >> 17;
    int r = id & 131071;
    int o = r >> 9, j = r & 511;
    const float* ow = dir ? vow : how;
    const float* nw = dir ? vnw : hnw;
    int off = dir ? 0 : 512;
    const float* fr = fc_w + o * 1024 + off;
    float acc = 0.f;
    for (int k = 0; k < 256; ++k) acc += (fr[k] + fr[256 + k]) * ow[k * 512 + j];
    Wc[id] = __float2bfloat16(nw[j] * acc);
  } else {
    int id = (b - 1024) * 256 + threadIdx.x;  // 598016 = 2*1168*256
    int dir = id / 299008;
    int r = id % 299008;
    int row = r >> 8;
    const float* src = dir ? vw : hw;
    float v = (row < 1160) ? src[r] : 0.f;
    inw[id] = __float2bfloat16(v);
  }
}

// LDS short-offsets (81408 B total -> 2 blocks/CU, proven in round 5)
#define OFS_U    0       // bf16 [64][264] staged u (alive whole kernel: A-frags)
#define OFS_R1   16896   // bf16 [128][65]: prologue BC raw; head loop z rows 0..63, x rows 64..127
#define OFS_X    25216   // bf16 [64][72] X [p][s]   (prologue: smB [s][n])
#define OFS_M    29824   // bf16 [64][72] M [t][s]   (prologue: smC [t][n])
#define OFS_GB   34432   // bf16 [64][72] g [t][j]   (prologue: dt raw [8][65])
#define OFS_CUM  39040   // fp32 [8][64]
#define OFS_DT   40064   // bf16 [8][64]
#define OFS_SSQ  40576   // fp32 [64]
#define SM_SHORTS 40704

template<int DIR>
__global__ __launch_bounds__(NTH, 4)
void mamba_dir_kernel(const float* __restrict__ x,
                      const __hip_bfloat16* __restrict__ inw_bf,  // [1168][256]
                      const float* __restrict__ conv_w,
                      const float* __restrict__ conv_b,
                      const float* __restrict__ dt_bias,
                      const float* __restrict__ A_log,
                      const float* __restrict__ Dvec,
                      const __hip_bfloat16* __restrict__ Wc,      // [256][512]
                      const float* __restrict__ fc_b,
                      float* __restrict__ out)
{
  __shared__ short sm[SM_SHORTS];
  short* smU   = sm + OFS_U;
  short* smR1  = sm + OFS_R1;
  short* smB   = sm + OFS_X;    // prologue alias
  short* smX   = sm + OFS_X;
  short* smC   = sm + OFS_M;    // prologue alias
  short* smM   = sm + OFS_M;
  short* smg   = sm + OFS_GB;
  short* dtraw = sm + OFS_GB;   // prologue alias
  float* smCUM = (float*)(sm + OFS_CUM);
  short* smDT  = sm + OFS_DT;
  float* smSSQ = (float*)(sm + OFS_SSQ);

  const int tid = threadIdx.x;
  const int t = tid & 63;
  const int w = tid >> 6;
  const int lane15 = tid & 15;
  const int quad = (tid & 63) >> 4;
  const int mt = w >> 1;               // wave's m-tile for G/M/Y/gating
  const int nt0 = (w & 1) * 2;         // wave's first n-tile for 64-col outputs
  const int s = blockIdx.x;

  auto MF = [](short8 a, short8 b, floatx4 c) -> floatx4 {
    return __builtin_amdgcn_mfma_f32_16x16x32_bf16(a, b, c, 0, 0, 0);
  };
  auto ldA_u = [&](int mtile, int kt) -> short8 {
    return *(const short8*)(smU + (mtile * 16 + lane15) * 264 + kt * 32 + quad * 8);
  };
  auto ldB_w = [&](int row0, int kt) -> short8 {
    return *(const short8*)((const short*)inw_bf + (row0 + lane15) * 256 + kt * 32 + quad * 8);
  };
  auto ldB_wc = [&](int o0, int hd, int kt) -> short8 {
    return *(const short8*)((const short*)Wc + (o0 + lane15) * 512 + hd * 64 + kt * 32 + quad * 8);
  };
  auto ld72 = [&](const short* base, int row, int kt) -> short8 {
    return *(const short8*)(base + row * 72 + kt * 32 + quad * 8);
  };
  // one n-tile (16 out-channels at weight row0) x all 64 t (4 m-tiles), K=256
  // dst points at channel-row base (stride 65 in t); may be null (pad rows)
  auto proj_tile = [&](int row0, short* dst) {
    floatx4 a0 = (floatx4)0.f, a1 = (floatx4)0.f, a2 = (floatx4)0.f, a3 = (floatx4)0.f;
#pragma unroll
    for (int kt = 0; kt < 8; ++kt) {
      short8 b = ldB_w(row0, kt);
      a0 = MF(ldA_u(0, kt), b, a0);
      a1 = MF(ldA_u(1, kt), b, a1);
      a2 = MF(ldA_u(2, kt), b, a2);
      a3 = MF(ldA_u(3, kt), b, a3);
    }
    if (dst) {
      short* d = dst + quad * 4;
#pragma unroll
      for (int r = 0; r < 4; ++r) {
        d[r]      = f2bs(a0[r]); d[16 + r] = f2bs(a1[r]);
        d[32 + r] = f2bs(a2[r]); d[48 + r] = f2bs(a3[r]);
      }
    }
  };

  long ubase; int ustride;
  if (DIR == 0) { ubase = (long)s * 16384; ustride = 256; }
  else { ubase = (long)(s >> 6) * 1048576 + (long)(s & 63) * 256; ustride = 16384; }

  // ---- stage u -> bf16 [t][264] ----
  for (int i = tid; i < 4096; i += NTH) {
    int tt = i >> 6, c4 = (i & 63) * 4;
    const float4 v = *(const float4*)(x + ubase + (long)tt * ustride + c4);
    uint2 pw; pw.x = pk2(v.x, v.y); pw.y = pk2(v.z, v.w);
    *(uint2*)(smU + tt * 264 + c4) = pw;
  }
  if (tid < 64) smSSQ[tid] = 0.f;
  __syncthreads();

  // ---- BCdt projection (rows 1024..1167, 9 n-tiles over 8 waves) ----
  for (int jt = w; jt < 9; jt += 8) {
    int q = jt * 16 + lane15;
    short* dst = (q < 128) ? (smR1 + q * 65)
               : (q < 136) ? (dtraw + (q - 128) * 65) : (short*)nullptr;
    proj_tile(1024 + jt * 16, dst);
  }
  __syncthreads();

  // ---- conv+silu B/C -> smB [s][n] / smC [t][n]; dt softplus + cum scan ----
  {
#pragma unroll
    for (int ii = 0; ii < 16; ++ii) {
      int q = w + ii * 8;            // 0..127
      int ch = 512 + q;
      const short* base = smR1 + q * 65 + t;
      float v3 = bs2f(base[0]);
      float v2 = (t >= 1) ? bs2f(base[-1]) : 0.f;
      float v1 = (t >= 2) ? bs2f(base[-2]) : 0.f;
      float v0 = (t >= 3) ? bs2f(base[-3]) : 0.f;
      const float4 cw = *(const float4*)(conv_w + ch * 4);
      float v = cw.x*v0 + cw.y*v1 + cw.z*v2 + cw.w*v3 + conv_b[ch];
      short sv = f2bs(silu_f(v));
      if (q < 64) smB[t * 72 + q] = sv;
      else        smC[t * 72 + (q - 64)] = sv;
    }
    float dtv = softplus_f(bs2f(dtraw[w * 65 + t]) + dt_bias[w]);
    smDT[w * 64 + t] = f2bs(dtv);
    float cum = -__expf(A_log[w]) * dtv;
#pragma unroll
    for (int off = 1; off < 64; off <<= 1) {
      float y = __shfl_up(cum, off, 64);
      if (t >= off) cum += y;
    }
    smCUM[w * 64 + t] = cum;
  }
  __syncthreads();

  // ---- G = C B^T via MFMA; STAYS IN REGISTERS (C-layout) ----
  // thread holds G[tr][p] for tr = mt*16+quad*4+r, p = (nt0+j)*16+lane15
  floatx4 Gr0 = (floatx4)0.f, Gr1 = (floatx4)0.f;
#pragma unroll
  for (int kt = 0; kt < 2; ++kt) {
    short8 a = ld72(smC, mt * 16 + lane15, kt);
    Gr0 = MF(a, ld72(smB, nt0 * 16 + lane15, kt), Gr0);
    Gr1 = MF(a, ld72(smB, (nt0 + 1) * 16 + lane15, kt), Gr1);
  }
  // no barrier: smB/smC (=smX/smM) rewritten only after B1 of head 0

  floatx4 accO[4][2];
#pragma unroll
  for (int m = 0; m < 4; ++m) { accO[m][0] = (floatx4)0.f; accO[m][1] = (floatx4)0.f; }
  float part[4] = {0.f, 0.f, 0.f, 0.f};

  for (int hd = 0; hd < 8; ++hd) {
    // P1: x/z head proj -> smR1 (z ch p -> row p; x ch p -> row 64+p)
    {
      int row0 = (w < 4) ? (hd * 64 + w * 16) : (512 + hd * 64 + (w - 4) * 16);
      int q = ((w < 4) ? w * 16 : 64 + (w - 4) * 16) + lane15;
      proj_tile(row0, smR1 + q * 65);
    }
    __syncthreads();                 // B1: z/x raw ready; smM/smX free

    // P2: conv+silu x -> smX [p][s]; M build from G regs (D on diagonal)
    {
#pragma unroll
      for (int ii = 0; ii < 8; ++ii) {
        int p = w + ii * 8, ch = hd * 64 + p;
        const short* base = smR1 + (64 + p) * 65 + t;
        float v3 = bs2f(base[0]);
        float v2 = (t >= 1) ? bs2f(base[-1]) : 0.f;
        float v1 = (t >= 2) ? bs2f(base[-2]) : 0.f;
        float v0 = (t >= 3) ? bs2f(base[-3]) : 0.f;
        const float4 cw = *(const float4*)(conv_w + ch * 4);
        float v = cw.x*v0 + cw.y*v1 + cw.z*v2 + cw.w*v3 + conv_b[ch];
        smX[p * 72 + t] = f2bs(silu_f(v));
      }
      const float* cumh = smCUM + hd * 64;
      const short* dth  = smDT + hd * 64;
      float Dh = Dvec[hd];
#pragma unroll
      for (int j = 0; j < 2; ++j) {
        int p = (nt0 + j) * 16 + lane15;
        float cp = cumh[p];
        float dp = bs2f(dth[p]);
        floatx4 gg = j ? Gr1 : Gr0;
#pragma unroll
        for (int r = 0; r < 4; ++r) {
          int tr = mt * 16 + quad * 4 + r;
          float m = 0.f;
          if (tr >= p) m = __expf(cumh[tr] - cp) * dp * gg[r];
          if (tr == p) m += Dh;
          smM[tr * 72 + p] = f2bs(m);
        }
      }
    }
    __syncthreads();                 // B2: smM/smX ready

    // P3: Y = M X via MFMA + silu(z) gating (z from smR1) -> smg; ssq in regs
    {
      floatx4 y0 = (floatx4)0.f, y1 = (floatx4)0.f;
#pragma unroll
      for (int kt = 0; kt < 2; ++kt) {
        short8 a = ld72(smM, mt * 16 + lane15, kt);
        y0 = MF(a, ld72(smX, nt0 * 16 + lane15, kt), y0);
        y1 = MF(a, ld72(smX, (nt0 + 1) * 16 + lane15, kt), y1);
      }
#pragma unroll
      for (int j = 0; j < 2; ++j) {
        floatx4 yy = j ? y1 : y0;
        int p = (nt0 + j) * 16 + lane15;
#pragma unroll
        for (int r = 0; r < 4; ++r) {
          int tr = mt * 16 + quad * 4 + r;
          float zv = bs2f(smR1[p * 65 + tr]);
          float g = yy[r] * silu_f(zv);
          part[r] += g * g;
          smg[tr * 72 + p] = f2bs(g);
        }
      }
    }
    __syncthreads();                 // B3: smg ready

    // P5: out-proj MFMA (g x Wc), 4 m-tiles per wave (4:1 amortization)
    {
#pragma unroll
      for (int kt = 0; kt < 2; ++kt) {
        short8 b0 = ldB_wc(w * 16, hd, kt);
        short8 b1 = ldB_wc((w + 8) * 16, hd, kt);
#pragma unroll
        for (int m = 0; m < 4; ++m) {
          short8 a = ld72(smg, m * 16 + lane15, kt);
          accO[m][0] = MF(a, b0, accO[m][0]);
          accO[m][1] = MF(a, b1, accO[m][1]);
        }
      }
    }
    // next P1 writes smR1 (disjoint from smg) then B1 guards smM/smX reuse
  }

  // ---- ssq: reduce over the 16 lanes sharing each row, 2 parity waves ----
#pragma unroll
  for (int r = 0; r < 4; ++r) {
    float v = part[r];
    v += __shfl_xor(v, 1, 64);
    v += __shfl_xor(v, 2, 64);
    v += __shfl_xor(v, 4, 64);
    v += __shfl_xor(v, 8, 64);
    if (lane15 == 0) atomicAdd(&smSSQ[mt * 16 + quad * 4 + r], v);
  }
  __syncthreads();
  if (tid < 64) smSSQ[tid] = rsqrtf(smSSQ[tid] * (1.f / 512.f) + 1e-5f);
  __syncthreads();

  // ---- epilogue: RMS scale, direct C-layout global writes ----
#pragma unroll
  for (int m = 0; m < 4; ++m) {
#pragma unroll
    for (int n = 0; n < 2; ++n) {
      int o = (w + n * 8) * 16 + lane15;
      float fb = (DIR == 0) ? fc_b[o] : 0.f;
#pragma unroll
      for (int r = 0; r < 4; ++r) {
        int tt = m * 16 + quad * 4 + r;
        float val = accO[m][n][r] * smSSQ[tt];
        long rowg = (DIR == 0) ? ((long)s * 64 + tt)
                               : ((long)(s >> 6) * 4096 + (long)tt * 64 + (s & 63));
        long gi = rowg * 256 + o;
        if (DIR == 0) out[gi] = fb + val;
        else          out[gi] += val;
      }
    }
  }
}

extern "C" void kernel_launch(void* const* d_in, const int* in_sizes, int n_in,
                              void* d_out, int out_size, void* d_ws, size_t ws_size,
                              hipStream_t stream) {
  const float* x          = (const float*)d_in[0];
  const float* mh_in_w    = (const float*)d_in[1];
  const float* mh_conv_w  = (const float*)d_in[2];
  const float* mh_conv_b  = (const float*)d_in[3];
  const float* mh_dt_bias = (const float*)d_in[4];
  const float* mh_A_log   = (const float*)d_in[5];
  const float* mh_D       = (const float*)d_in[6];
  const float* mh_norm_w  = (const float*)d_in[7];
  const float* mh_out_w   = (const float*)d_in[8];
  const float* mv_in_w    = (const float*)d_in[9];
  const float* mv_conv_w  = (const float*)d_in[10];
  const float* mv_conv_b  = (const float*)d_in[11];
  const float* mv_dt_bias = (const float*)d_in[12];
  const float* mv_A_log   = (const float*)d_in[13];
  const float* mv_D       = (const float*)d_in[14];
  const float* mv_norm_w  = (const float*)d_in[15];
  const float* mv_out_w   = (const float*)d_in[16];
  const float* fc_w       = (const float*)d_in[17];
  const float* fc_b       = (const float*)d_in[18];
  float* out = (float*)d_out;

  __hip_bfloat16* Wcb  = (__hip_bfloat16*)d_ws;                       // 2*131072 bf16
  __hip_bfloat16* inwb = (__hip_bfloat16*)((char*)d_ws + 524288);     // 2*1168*256 bf16

  setup_weights<<<3360, 256, 0, stream>>>(fc_w, mh_out_w, mh_norm_w, mv_out_w, mv_norm_w,
                                          mh_in_w, mv_in_w, Wcb, inwb);
  mamba_dir_kernel<0><<<512, NTH, 0, stream>>>(x, inwb, mh_conv_w, mh_conv_b,
      mh_dt_bias, mh_A_log, mh_D, Wcb, fc_b, out);
  mamba_dir_kernel<1><<<512, NTH, 0, stream>>>(x, inwb + 299008, mv_conv_w, mv_conv_b,
      mv_dt_bias, mv_A_log, mv_D, Wcb + 131072, fc_b, out);
}